// Round 7
// baseline (9943.596 us; speedup 1.0000x reference)
//
#include <hip/hip_runtime.h>
#include <hip/hip_fp16.h>

#define GD 256   // grid (workgroups) -- must be <= CU count for residency
#define BD 256   // block

constexpr int TSTEPS = 256; // sequence length
constexpr int DD = 512;     // d_in = d_out = d_ctx = a_hid
constexpr int KK4 = 2048;   // 4*D_OUT
constexpr int LC = 128;     // context length

constexpr int PCOLS = 26;   // packed cols per WG: 8 W + 8 U + 8 V + 2 Wh (fp16)
constexpr int PSZH  = PCOLS * DD;  // 13312 halves per WG

// ---- workspace layout (float offsets) ----
constexpr size_t OFF_HATT  = 0;                       // [32][512] fp32 (coherent)
constexpr size_t OFF_FLAGS = 16384;                   // 256 arrival flags, stride 32 ints
constexpr size_t OFF_REL   = OFF_FLAGS + 8192;        // 8 release lines, stride 32 ints
constexpr size_t OFF_WCTXR = 24832;                   // ring: [256][32][512] fp32 (atomics)
constexpr size_t OFF_ZR    = OFF_WCTXR + 4194304;     // ring: [256][64] fp32
constexpr size_t OFF_ATT16 = OFF_ZR + 16384;          // [4096][512] fp16 (1048576 floats)
constexpr size_t OFF_PACK16= OFF_ATT16 + 1048576;     // [256][13312] fp16 (1703936 floats)
constexpr size_t OFF_HRING = OFF_PACK16 + 1703936;    // ring: [256][32][512] fp16 (2097152 floats)
constexpr size_t WS_FLOATS = OFF_HRING + 2097152;     // ~36.3 MB

typedef _Float16 h16;
typedef _Float16 h2  __attribute__((ext_vector_type(2)));
typedef _Float16 h8v __attribute__((ext_vector_type(8)));
union H8  { h8v v; h2 p[4]; };
union H2U { h2 h; unsigned u; };

__device__ __forceinline__ float rcp_fast(float x) { return __builtin_amdgcn_rcpf(x); }
__device__ __forceinline__ float ftanh(float x) {
  float e = __expf(2.0f * x);
  return 1.0f - 2.0f * rcp_fast(e + 1.0f);
}
__device__ __forceinline__ float fsig(float x) { return rcp_fast(1.0f + __expf(-x)); }

__device__ __forceinline__ float fdot2(h2 a, h2 b, float c) {
  return __builtin_amdgcn_fdot2(a, b, c, false);   // v_dot2_f32_f16
}

// coherent (agent-scope, L2-bypassing) access -- does NOT invalidate L2
__device__ __forceinline__ float cload(const float* p) {
  return __hip_atomic_load(p, __ATOMIC_RELAXED, __HIP_MEMORY_SCOPE_AGENT);
}
__device__ __forceinline__ void cstore(float* p, float v) {
  __hip_atomic_store(p, v, __ATOMIC_RELAXED, __HIP_MEMORY_SCOPE_AGENT);
}
__device__ __forceinline__ void cstoreu(unsigned* p, unsigned v) {
  __hip_atomic_store(p, v, __ATOMIC_RELAXED, __HIP_MEMORY_SCOPE_AGENT);
}

// grid barrier, no atomic RMW: per-WG flag lines + WG0 parallel scan + 8 release lines
__device__ __forceinline__ void gsync(int* flags, int* rel, int w, int& gen) {
  __syncthreads();
  gen++;
  const int t = threadIdx.x;
  if (w == 0) {
    if (t < 64) {
      if (t == 0)
        __hip_atomic_store(flags, gen, __ATOMIC_RELAXED, __HIP_MEMORY_SCOPE_AGENT);
      for (;;) {
        int m = gen;
#pragma unroll
        for (int i = 0; i < 4; i++) {
          int v = __hip_atomic_load(flags + (t + i * 64) * 32,
                                    __ATOMIC_RELAXED, __HIP_MEMORY_SCOPE_AGENT);
          m = (v < m) ? v : m;
        }
        if (__all(m >= gen)) break;
      }
      if (t == 0) {
#pragma unroll
        for (int i = 0; i < 8; i++)
          __hip_atomic_store(rel + i * 32, gen, __ATOMIC_RELAXED,
                             __HIP_MEMORY_SCOPE_AGENT);
      }
    }
    asm volatile("" ::: "memory");
  } else {
    if (t == 0) {
      __hip_atomic_store(flags + w * 32, gen, __ATOMIC_RELAXED,
                         __HIP_MEMORY_SCOPE_AGENT);
      const int* r = rel + (w & 7) * 32;
      while (__hip_atomic_load(r, __ATOMIC_RELAXED, __HIP_MEMORY_SCOPE_AGENT) < gen)
        __builtin_amdgcn_s_sleep(1);
    }
    asm volatile("" ::: "memory");
  }
  __syncthreads();
}

// xw_t for this WG's 8 preact cols; x fp32 -> cvt fp16 -> fdot2 with fp16 weights.
__device__ __forceinline__ float xw_compute(float* buf, const float* __restrict__ x,
                                            const h16* __restrict__ PW16, int tt,
                                            int b2g, int c2g) {
  const int t = threadIdx.x, b = t & 31, s = t >> 5, k0 = s * 64;
  const float* xrow = x + ((size_t)b * TSTEPS + tt) * DD + k0;
  const h16* Pk = PW16 + k0;
  float acc[8] = {0.f,0.f,0.f,0.f,0.f,0.f,0.f,0.f};
#pragma unroll 2
  for (int kk = 0; kk < 64; kk += 8) {
    float4 xa = *(const float4*)(xrow + kk);
    float4 xb = *(const float4*)(xrow + kk + 4);
    h2 x0 = {(h16)xa.x, (h16)xa.y}, x1 = {(h16)xa.z, (h16)xa.w};
    h2 x2 = {(h16)xb.x, (h16)xb.y}, x3 = {(h16)xb.z, (h16)xb.w};
#pragma unroll
    for (int c = 0; c < 8; c++) {
      H8 wv; wv.v = *(const h8v*)(Pk + c * DD + kk);
      acc[c] = fdot2(x0, wv.p[0], acc[c]);
      acc[c] = fdot2(x1, wv.p[1], acc[c]);
      acc[c] = fdot2(x2, wv.p[2], acc[c]);
      acc[c] = fdot2(x3, wv.p[3], acc[c]);
    }
  }
  __syncthreads();                       // previous buf users done
#pragma unroll
  for (int cc = 0; cc < 8; cc++) buf[(cc * 8 + s) * 32 + b] = acc[cc];
  __syncthreads();
  float sum = 0.f;
#pragma unroll
  for (int s2 = 0; s2 < 8; s2++) sum += buf[(c2g * 8 + s2) * 32 + b2g];
  return sum;
}

__global__ __launch_bounds__(BD, 1) void attn_lstm_persistent(
    const float* __restrict__ x, const float* __restrict__ ctx,
    const float* __restrict__ W, const float* __restrict__ V,
    const float* __restrict__ U, const float* __restrict__ bias,
    const float* __restrict__ Wh, const float* __restrict__ Wc,
    const float* __restrict__ batt, const float* __restrict__ wprj,
    float* __restrict__ out, float* __restrict__ ws) {
  __shared__ float buf[8192];            // 32 KB (setup staging + reductions)
  __shared__ float aux[576];
  const int w = blockIdx.x;
  const int t = threadIdx.x;
  float* hatt  = ws + OFF_HATT;
  float* wctxr = ws + OFF_WCTXR;
  float* Zr    = ws + OFF_ZR;
  h16*   att16 = (h16*)(ws + OFF_ATT16);
  h16*   hring = (h16*)(ws + OFF_HRING);
  h16*   packb = (h16*)(ws + OFF_PACK16) + (size_t)w * PSZH;
  int*   flags = (int*)(ws + OFF_FLAGS);
  int*   rel   = (int*)(ws + OFF_REL);
  int gen = 0;

  const int b2g = t & 31, c2g = t >> 5;          // thread->output mapping
  const int d0 = w * 2;
  const int mycol = d0 + (c2g & 1) + (c2g >> 1) * 512;
  const float bias_reg = bias[mycol];

  float xw_cur, xw_next = 0.f, hU_reg;
  float c_reg = 0.f;                              // t<64 threads own c[(t&31)][2w+(t>>5)]

  // ---------------- setup A: pack this WG's 26 weight columns, fp16, k-contiguous ----
  {
#pragma unroll 4
    for (int i = 0; i < PCOLS * 2; i++) {         // 52 iterations x 256 threads
      int e = i * BD + t;
      int pc = e >> 9, k = e & 511;
      float v;
      if (pc < 8)       v = W[(size_t)k * KK4 + d0 + (pc & 1) + (pc >> 1) * 512];
      else if (pc < 16) { int q = pc - 8;  v = U[(size_t)k * KK4 + d0 + (q & 1) + (q >> 1) * 512]; }
      else if (pc < 24) { int q = pc - 16; v = V[(size_t)k * KK4 + d0 + (q & 1) + (q >> 1) * 512]; }
      else              v = Wh[(size_t)k * DD + d0 + (pc - 24)];
      packb[e] = (h16)v;
    }
  }
  const h16* PW16  = packb;
  const h16* PU16  = packb + 8 * DD;
  const h16* PV16  = packb + 16 * DD;
  const h16* PWh16 = packb + 24 * DD;
  __syncthreads();

  // ---------------- setup B: att16 = fp16(context @ Wc + b_att) (WG-local rows) ----
  {
    const int r0 = w * 16;
    for (int i = 0; i < 8; i++) {
      int idx4 = i * BD + t;
      int row = idx4 >> 7, c4 = idx4 & 127;
      ((float4*)buf)[idx4] = ((const float4*)(ctx + (size_t)(r0 + row) * DD))[c4];
    }
    __syncthreads();
    float accA[16], accB[16];
#pragma unroll
    for (int r = 0; r < 16; r++) { accA[r] = 0.f; accB[r] = 0.f; }
    const int a0 = t, a1 = t + 256;
    for (int cc = 0; cc < DD; cc++) {
      float w0 = Wc[(size_t)cc * DD + a0];
      float w1 = Wc[(size_t)cc * DD + a1];
#pragma unroll
      for (int r = 0; r < 16; r++) {
        float cv = buf[r * DD + cc];
        accA[r] += cv * w0; accB[r] += cv * w1;
      }
    }
    const float ba0 = batt[a0], ba1 = batt[a1];
    for (int r = 0; r < 16; r++) {
      att16[(size_t)(r0 + r) * DD + a0] = (h16)(accA[r] + ba0);  // WG-local
      att16[(size_t)(r0 + r) * DD + a1] = (h16)(accB[r] + ba1);
    }
    __syncthreads();
  }
  xw_cur = xw_compute(buf, x, PW16, 0, b2g, c2g);
  gsync(flags, rel, w, gen);

  // ---------------- recurrence ----------------
  for (int step = 0; step < TSTEPS; step++) {
    // ---- S1: hU (8 own cols -> reg) + hatt (2 cols, coherent store).
    //      h_{step-1} read from fp16 ring (fresh lines, L2-dedup'd across WGs). ----
    {
      const int b = t & 31, s = t >> 5, k0 = s * 64;
      float acc[10];
#pragma unroll
      for (int i = 0; i < 10; i++) acc[i] = 0.f;
      if (step > 0) {
        const h16* hrow = hring + (size_t)(step - 1) * 16384 + (size_t)b * DD + k0;
        const h16* Pk   = PU16 + k0;
        const h16* Pw   = PWh16 + k0;
#pragma unroll 2
        for (int kk = 0; kk < 64; kk += 8) {
          H8 hv; hv.v = *(const h8v*)(hrow + kk);
#pragma unroll
          for (int c = 0; c < 8; c++) {
            H8 wv; wv.v = *(const h8v*)(Pk + c * DD + kk);
            acc[c] = fdot2(hv.p[0], wv.p[0], acc[c]);
            acc[c] = fdot2(hv.p[1], wv.p[1], acc[c]);
            acc[c] = fdot2(hv.p[2], wv.p[2], acc[c]);
            acc[c] = fdot2(hv.p[3], wv.p[3], acc[c]);
          }
          H8 w0; w0.v = *(const h8v*)(Pw + kk);
          H8 w1; w1.v = *(const h8v*)(Pw + DD + kk);
          acc[8] = fdot2(hv.p[0], w0.p[0], acc[8]);
          acc[8] = fdot2(hv.p[1], w0.p[1], acc[8]);
          acc[8] = fdot2(hv.p[2], w0.p[2], acc[8]);
          acc[8] = fdot2(hv.p[3], w0.p[3], acc[8]);
          acc[9] = fdot2(hv.p[0], w1.p[0], acc[9]);
          acc[9] = fdot2(hv.p[1], w1.p[1], acc[9]);
          acc[9] = fdot2(hv.p[2], w1.p[2], acc[9]);
          acc[9] = fdot2(hv.p[3], w1.p[3], acc[9]);
        }
      }
#pragma unroll
      for (int cc = 0; cc < 10; cc++) buf[(cc * 8 + s) * 32 + b] = acc[cc];
      __syncthreads();
      float hu = 0.f;
#pragma unroll
      for (int s2 = 0; s2 < 8; s2++) hu += buf[(c2g * 8 + s2) * 32 + b2g];
      hU_reg = hu;
      if (t < 64) {
        const int b3 = t & 31, j = t >> 5;
        float sum = 0.f;
#pragma unroll
        for (int s2 = 0; s2 < 8; s2++) sum += buf[((8 + j) * 8 + s2) * 32 + b3];
        cstore(hatt + (size_t)b3 * DD + d0 + j, sum);
      }
    }
    gsync(flags, rel, w, gen);

    // ---- S2: attention scores + unnormalized wctx into ring slot; prefetch xw[t+1] ----
    {
      float* wslot = wctxr + (size_t)step * 16384;
      float* zslot = Zr + (size_t)step * 64;
      const int b = w >> 3, l0 = (w & 7) * 16;
      aux[t]       = cload(hatt + (size_t)b * DD + t);
      aux[256 + t] = cload(hatt + (size_t)b * DD + 256 + t);
      __syncthreads();
      const int l = t >> 4, u = t & 15;
      const h16* ar = att16 + (size_t)(b * LC + l0 + l) * DD;
      float p = 0.f;
#pragma unroll
      for (int j = 0; j < 4; j++) {
        int a8 = j * 16 + u;
        H8 av; av.v = *(const h8v*)(ar + a8 * 8);
        int a0 = a8 * 8;
        float4 w0 = *(const float4*)(wprj + a0);
        float4 w1 = *(const float4*)(wprj + a0 + 4);
        p += ftanh((float)av.v[0] + aux[a0+0]) * w0.x
           + ftanh((float)av.v[1] + aux[a0+1]) * w0.y
           + ftanh((float)av.v[2] + aux[a0+2]) * w0.z
           + ftanh((float)av.v[3] + aux[a0+3]) * w0.w
           + ftanh((float)av.v[4] + aux[a0+4]) * w1.x
           + ftanh((float)av.v[5] + aux[a0+5]) * w1.y
           + ftanh((float)av.v[6] + aux[a0+6]) * w1.z
           + ftanh((float)av.v[7] + aux[a0+7]) * w1.w;
      }
      p += __shfl_xor(p, 8); p += __shfl_xor(p, 4);
      p += __shfl_xor(p, 2); p += __shfl_xor(p, 1);
      if (u == 0) {
        float uv = __expf(p);
        aux[512 + l] = uv;
        atomicAdd(&zslot[b], uv);
      }
      __syncthreads();
      float s0 = 0.f, s1 = 0.f;
      const float* cr = ctx + (size_t)(b * LC + l0) * DD;
#pragma unroll 4
      for (int l2 = 0; l2 < 16; l2++) {
        float uv = aux[512 + l2];
        s0 += uv * cr[l2 * DD + t];
        s1 += uv * cr[l2 * DD + t + 256];
      }
      atomicAdd(&wslot[(size_t)b * DD + t], s0);
      atomicAdd(&wslot[(size_t)b * DD + t + 256], s1);
      if (step + 1 < TSTEPS) xw_next = xw_compute(buf, x, PW16, step + 1, b2g, c2g);
    }
    gsync(flags, rel, w, gen);

    // ---- S3: preact = xw + hU + (wctx/Z)@V + bias; gates; h/c update ----
    {
      const int b = t & 31, s = t >> 5, k0 = s * 64;
      if (t < 32) aux[t] = Zr[(size_t)step * 64 + t];
      __syncthreads();
      const float rz = rcp_fast(aux[b]);
      const float* wrow = wctxr + (size_t)step * 16384 + (size_t)b * DD + k0;
      const h16* Pk = PV16 + k0;
      float acc[8] = {0.f,0.f,0.f,0.f,0.f,0.f,0.f,0.f};
#pragma unroll 2
      for (int kk = 0; kk < 64; kk += 8) {
        float4 wa = *(const float4*)(wrow + kk);
        float4 wb = *(const float4*)(wrow + kk + 4);
        h2 c0 = {(h16)(wa.x * rz), (h16)(wa.y * rz)};
        h2 c1 = {(h16)(wa.z * rz), (h16)(wa.w * rz)};
        h2 c2 = {(h16)(wb.x * rz), (h16)(wb.y * rz)};
        h2 c3 = {(h16)(wb.z * rz), (h16)(wb.w * rz)};
#pragma unroll
        for (int c = 0; c < 8; c++) {
          H8 wv; wv.v = *(const h8v*)(Pk + c * DD + kk);
          acc[c] = fdot2(c0, wv.p[0], acc[c]);
          acc[c] = fdot2(c1, wv.p[1], acc[c]);
          acc[c] = fdot2(c2, wv.p[2], acc[c]);
          acc[c] = fdot2(c3, wv.p[3], acc[c]);
        }
      }
      __syncthreads();
#pragma unroll
      for (int cc = 0; cc < 8; cc++) buf[(cc * 8 + s) * 32 + b] = acc[cc];
      __syncthreads();
      {
        float sum = 0.f;
#pragma unroll
        for (int s2 = 0; s2 < 8; s2++) sum += buf[(c2g * 8 + s2) * 32 + b2g];
        sum += xw_cur + hU_reg + bias_reg;
        buf[2048 + c2g * 32 + b2g] = sum;
      }
      __syncthreads();
      if (t < 64) {
        const int b3 = t & 31, dd = t >> 5;
        const int d = d0 + dd;
        float pi = buf[2048 + (0 + dd) * 32 + b3];
        float pf = buf[2048 + (2 + dd) * 32 + b3];
        float po = buf[2048 + (4 + dd) * 32 + b3];
        float pg = buf[2048 + (6 + dd) * 32 + b3];
        float ig = fsig(pi), fg = fsig(pf), og = fsig(po), gg = ftanh(pg);
        float cn = fg * c_reg + ig * gg;
        c_reg = cn;
        float hn = og * ftanh(cn);
        out[(size_t)b3 * (TSTEPS * DD) + (size_t)step * DD + d] = hn; // plain store
        float hn2 = __shfl(hn, (t & 31) + 32);    // partner lane's value (dd=1)
        if (t < 32) {                             // pack (d0, d0+1) as fp16 pair
          H2U pu; pu.h = h2{(h16)hn, (h16)hn2};
          cstoreu((unsigned*)(hring + (size_t)step * 16384 + (size_t)t * DD + d0), pu.u);
        }
      }
      xw_cur = xw_next;
    }
    gsync(flags, rel, w, gen);
  }
}

extern "C" void kernel_launch(void* const* d_in, const int* in_sizes, int n_in,
                              void* d_out, int out_size, void* d_ws, size_t ws_size,
                              hipStream_t stream) {
  (void)in_sizes; (void)n_in; (void)out_size; (void)ws_size;
  const float* x    = (const float*)d_in[0];
  const float* ctx  = (const float*)d_in[1];
  const float* W    = (const float*)d_in[2];
  const float* V    = (const float*)d_in[3];
  const float* U    = (const float*)d_in[4];
  const float* b    = (const float*)d_in[5];
  const float* Wh   = (const float*)d_in[6];
  const float* Wc   = (const float*)d_in[7];
  const float* batt = (const float*)d_in[8];
  const float* wprj = (const float*)d_in[9];

  // zero the wctx/Z rings (accumulated by atomics) and barrier flags/release
  hipMemsetAsync((char*)d_ws + OFF_WCTXR * sizeof(float), 0,
                 (4194304 + 16384) * sizeof(float), stream);
  hipMemsetAsync((char*)d_ws + OFF_FLAGS * sizeof(float), 0,
                 (8192 + 256) * sizeof(int), stream);

  hipLaunchKernelGGL(attn_lstm_persistent, dim3(GD), dim3(BD), 0, stream,
                     x, ctx, W, V, U, b, Wh, Wc, batt, wprj,
                     (float*)d_out, (float*)d_ws);
}

// Round 8
// 9753.043 us; speedup vs baseline: 1.0195x; 1.0195x over previous
//
#include <hip/hip_runtime.h>
#include <hip/hip_fp16.h>

#define GD 256   // grid (workgroups) -- must be <= CU count for residency
#define BD 256   // block

constexpr int TSTEPS = 256; // sequence length
constexpr int DD = 512;     // d_in = d_out = d_ctx = a_hid
constexpr int KK4 = 2048;   // 4*D_OUT
constexpr int LC = 128;     // context length

// ---- workspace layout ----
// float-offset regions: flags [0..8192) ints, release [8192..8448) ints,
// then an h16 region starting at float offset 8448.
constexpr size_t OFF_FLAGS_F = 0;       // 256 flag lines (stride 32 ints)
constexpr size_t OFF_REL_F   = 8192;    // 8 release lines (stride 32 ints)
constexpr size_t OFF_H16_F   = 8448;    // h16 region base (float offset)
// h16-unit offsets inside the h16 region:
constexpr size_t HOFF_ATT   = 0;        // att16 [32][128][512]
constexpr size_t HOFF_CTX   = 2097152;  // ctx16 [32][128][512]
constexpr size_t HOFF_PACK  = 4194304;  // packWUV [8 g][3 mat][64 kb][256 c][8]
constexpr size_t HOFF_WHP   = 7340032;  // Whp [64 kb][512 c][8]
constexpr size_t HOFF_HRING = 7602176;  // hring [256 t][32 b][512]
// total h16 = 11,796,480 (~23.6 MB incl. flags) -- well under prior 36 MB usage

typedef _Float16 h16;
typedef _Float16 h2  __attribute__((ext_vector_type(2)));
typedef _Float16 h8v __attribute__((ext_vector_type(8)));
union H8  { h8v v; h2 p[4]; };
union H2U { h2 h; unsigned u; };

__device__ __forceinline__ float rcp_fast(float x) { return __builtin_amdgcn_rcpf(x); }
__device__ __forceinline__ float ftanh(float x) {
  float e = __expf(2.0f * x);
  return 1.0f - 2.0f * rcp_fast(e + 1.0f);
}
__device__ __forceinline__ float fsig(float x) { return rcp_fast(1.0f + __expf(-x)); }
__device__ __forceinline__ float fdot2(h2 a, h2 b, float c) {
  return __builtin_amdgcn_fdot2(a, b, c, false);   // v_dot2_f32_f16
}

// coherent (agent-scope) access -- bypasses L1/L2, lands at MALL, no invalidation
__device__ __forceinline__ void cstoreu(unsigned* p, unsigned v) {
  __hip_atomic_store(p, v, __ATOMIC_RELAXED, __HIP_MEMORY_SCOPE_AGENT);
}

// grid barrier, no atomic RMW: per-WG flag lines + WG0 parallel scan + 8 release lines
__device__ __forceinline__ void gsync(int* flags, int* rel, int w, int& gen) {
  __syncthreads();
  gen++;
  const int t = threadIdx.x;
  if (w == 0) {
    if (t < 64) {
      if (t == 0)
        __hip_atomic_store(flags, gen, __ATOMIC_RELAXED, __HIP_MEMORY_SCOPE_AGENT);
      for (;;) {
        int m = gen;
#pragma unroll
        for (int i = 0; i < 4; i++) {
          int v = __hip_atomic_load(flags + (t + i * 64) * 32,
                                    __ATOMIC_RELAXED, __HIP_MEMORY_SCOPE_AGENT);
          m = (v < m) ? v : m;
        }
        if (__all(m >= gen)) break;
      }
      if (t == 0) {
#pragma unroll
        for (int i = 0; i < 8; i++)
          __hip_atomic_store(rel + i * 32, gen, __ATOMIC_RELAXED,
                             __HIP_MEMORY_SCOPE_AGENT);
      }
    }
    asm volatile("" ::: "memory");
  } else {
    if (t == 0) {
      __hip_atomic_store(flags + w * 32, gen, __ATOMIC_RELAXED,
                         __HIP_MEMORY_SCOPE_AGENT);
      const int* r = rel + (w & 7) * 32;
      while (__hip_atomic_load(r, __ATOMIC_RELAXED, __HIP_MEMORY_SCOPE_AGENT) < gen)
        __builtin_amdgcn_s_sleep(1);
    }
    asm volatile("" ::: "memory");
  }
  __syncthreads();
}

__global__ __launch_bounds__(BD, 1) void attn_lstm_persistent(
    const float* __restrict__ x, const float* __restrict__ ctx,
    const float* __restrict__ W, const float* __restrict__ V,
    const float* __restrict__ U, const float* __restrict__ bias,
    const float* __restrict__ Wh, const float* __restrict__ Wc,
    const float* __restrict__ batt, const float* __restrict__ wprj,
    float* __restrict__ out, float* __restrict__ ws) {
  __shared__ float buf[8192];                  // 32 KB, setup staging only
  __shared__ __align__(16) h16 haux[512];      // h_{t-1}[b,:]
  __shared__ __align__(16) h16 xaux[512];      // fp16(x[b,t,:])
  __shared__ __align__(16) h16 waux[512];      // fp16(wctx[b,:])
  __shared__ float hattf[512];                 // h@Wh (fp32)
  __shared__ float sexp[128];                  // exp(prj) -> alpha
  __shared__ float pre[256];                   // preact exchange
  __shared__ float wprjs[512];                 // staged w_att_prj
  __shared__ float zinv_sh;

  const int w = blockIdx.x;
  const int t = threadIdx.x;
  int*  flags = (int*)(ws + OFF_FLAGS_F);
  int*  rel   = (int*)(ws + OFF_REL_F);
  h16*  hb    = (h16*)(ws + OFF_H16_F);
  h16*  att16 = hb + HOFF_ATT;
  h16*  ctx16 = hb + HOFF_CTX;
  h16*  packW = hb + HOFF_PACK;
  h16*  Whp   = hb + HOFF_WHP;
  h16*  hring = hb + HOFF_HRING;
  int gen = 0;

  // XCD-aware (b,g) mapping: per XCD (w%8): 8 distinct b, 4 distinct g
  const int xcd = w & 7, j = w >> 3;
  const int b = (j & 7) | ((xcd >> 1) << 3);   // 0..31
  const int g = (j >> 3) | ((xcd & 1) << 2);   // 0..7

  const int cth = t;                           // this thread's col index in [0,256)
  const int mycol = 64 * g + (cth & 63) + ((cth >> 6) << 9);
  const float bias_reg = bias[mycol];
  float c_reg = 0.f;                           // t<64 own c[b][64g+t]

  // ---- stage wprj into LDS ----
  wprjs[t] = wprj[t];
  wprjs[t + 256] = wprj[t + 256];

  // ---- setup 1: pack W/U/V cols of group g (this WG packs 8 cols: j slice) ----
  {
    const int jj = w & 31, gg = w >> 5;        // pack ownership: 32 WGs per g
#pragma unroll
    for (int mat = 0; mat < 3; mat++) {
      const float* src = (mat == 0) ? W : ((mat == 1) ? U : V);
      h16* dst = packW + ((size_t)gg * 3 + mat) * 131072;
      for (int cc = 0; cc < 8; cc++) {
        int c = 8 * jj + cc;
        int col = 64 * gg + (c & 63) + ((c >> 6) << 9);
        int k0 = 2 * t;
        float v0 = src[(size_t)k0 * KK4 + col];
        float v1 = src[(size_t)(k0 + 1) * KK4 + col];
        H2U pu; pu.h = h2{(h16)v0, (h16)v1};
        cstoreu((unsigned*)(dst + (size_t)(k0 >> 3) * 2048 + c * 8 + (k0 & 7)), pu.u);
      }
    }
    if (w < 64) {                              // pack Wh cols [8w, 8w+8)
      for (int cc = 0; cc < 8; cc++) {
        int c = 8 * w + cc;
        int k0 = 2 * t;
        float v0 = Wh[(size_t)k0 * DD + c];
        float v1 = Wh[(size_t)(k0 + 1) * DD + c];
        H2U pu; pu.h = h2{(h16)v0, (h16)v1};
        cstoreu((unsigned*)(Whp + (size_t)(k0 >> 3) * 4096 + c * 8 + (k0 & 7)), pu.u);
      }
    }
  }

  // ---- setup 2: ctx16 = fp16(ctx), WG-sliced ----
  {
    const size_t base = (size_t)w * 8192;
    for (int i = 0; i < 8; i++) {
      size_t e = base + (size_t)i * 1024 + 4 * t;
      float4 v = *(const float4*)(ctx + e);
      H2U p0; p0.h = h2{(h16)v.x, (h16)v.y};
      H2U p1; p1.h = h2{(h16)v.z, (h16)v.w};
      cstoreu((unsigned*)(ctx16 + e), p0.u);
      cstoreu((unsigned*)(ctx16 + e + 2), p1.u);
    }
  }

  // ---- setup 3: att16 = fp16(ctx @ Wc + b_att), 16 rows per WG ----
  {
    const int r0 = w * 16;
    for (int i = 0; i < 8; i++) {
      int idx4 = i * BD + t;
      int row = idx4 >> 7, c4 = idx4 & 127;
      ((float4*)buf)[idx4] = ((const float4*)(ctx + (size_t)(r0 + row) * DD))[c4];
    }
    __syncthreads();
    float accA[16], accB[16];
#pragma unroll
    for (int r = 0; r < 16; r++) { accA[r] = 0.f; accB[r] = 0.f; }
    const int a0 = 2 * t, a1 = 2 * t + 1;
    for (int cc = 0; cc < DD; cc++) {
      float w0 = Wc[(size_t)cc * DD + a0];
      float w1 = Wc[(size_t)cc * DD + a1];
#pragma unroll
      for (int r = 0; r < 16; r++) {
        float cv = buf[r * DD + cc];           // LDS broadcast
        accA[r] += cv * w0; accB[r] += cv * w1;
      }
    }
    const float ba0 = batt[a0], ba1 = batt[a1];
    for (int r = 0; r < 16; r++) {
      H2U pu; pu.h = h2{(h16)(accA[r] + ba0), (h16)(accB[r] + ba1)};
      cstoreu((unsigned*)(att16 + (size_t)(r0 + r) * DD + a0), pu.u);
    }
  }
  gsync(flags, rel, w, gen);

  // ---------------- recurrence: ONE grid barrier per step ----------------
  const h16* myWp = packW + (size_t)g * 3 * 131072;
  const h16* myUp = myWp + 131072;
  const h16* myVp = myWp + 262144;
  const h16* attb = att16 + (size_t)b * LC * DD;
  const h16* ctxb = ctx16 + (size_t)b * LC * DD;

  for (int step = 0; step < TSTEPS; step++) {
    // ---- load h_{t-1}[b,:] and fp16(x[b,step,:]) into LDS ----
    if (t < 128) {
      if (step > 0) {
        ((uint2*)haux)[t] =
            *(const uint2*)(hring + ((size_t)(step - 1) * 32 + b) * DD + 4 * t);
      } else {
        ((uint2*)haux)[t] = make_uint2(0u, 0u);
      }
      float4 xv = *(const float4*)(x + ((size_t)b * TSTEPS + step) * DD + 4 * t);
      H2U p0; p0.h = h2{(h16)xv.x, (h16)xv.y};
      H2U p1; p1.h = h2{(h16)xv.z, (h16)xv.w};
      ((uint2*)xaux)[t] = make_uint2(p0.u, p1.u);
    }
    __syncthreads();

    // ---- hatt[b, 2t], hatt[b, 2t+1] = h @ Wh ----
    {
      float a0 = 0.f, a1 = 0.f;
      for (int kb = 0; kb < 64; kb++) {
        H8 hv; hv.v = *(const h8v*)(haux + kb * 8);          // broadcast
        H8 w0; w0.v = *(const h8v*)(Whp + (size_t)kb * 4096 + (2 * t) * 8);
        H8 w1; w1.v = *(const h8v*)(Whp + (size_t)kb * 4096 + (2 * t + 1) * 8);
        a0 = fdot2(hv.p[0], w0.p[0], a0); a0 = fdot2(hv.p[1], w0.p[1], a0);
        a0 = fdot2(hv.p[2], w0.p[2], a0); a0 = fdot2(hv.p[3], w0.p[3], a0);
        a1 = fdot2(hv.p[0], w1.p[0], a1); a1 = fdot2(hv.p[1], w1.p[1], a1);
        a1 = fdot2(hv.p[2], w1.p[2], a1); a1 = fdot2(hv.p[3], w1.p[3], a1);
      }
      hattf[2 * t] = a0; hattf[2 * t + 1] = a1;
    }
    __syncthreads();

    // ---- scores: thread (l = t>>1, half = t&1) over 256 a-values ----
    {
      const int l = t >> 1, half = t & 1, ab = half * 256;
      const h16* ar = attb + (size_t)l * DD + ab;
      const float* hf = hattf + ab;
      const float* wp = wprjs + ab;
      float p = 0.f;
      for (int i = 0; i < 32; i++) {
        H8 av; av.v = *(const h8v*)(ar + i * 8);
        int a8 = i * 8;
        p += ftanh((float)av.v[0] + hf[a8+0]) * wp[a8+0]
           + ftanh((float)av.v[1] + hf[a8+1]) * wp[a8+1]
           + ftanh((float)av.v[2] + hf[a8+2]) * wp[a8+2]
           + ftanh((float)av.v[3] + hf[a8+3]) * wp[a8+3]
           + ftanh((float)av.v[4] + hf[a8+4]) * wp[a8+4]
           + ftanh((float)av.v[5] + hf[a8+5]) * wp[a8+5]
           + ftanh((float)av.v[6] + hf[a8+6]) * wp[a8+6]
           + ftanh((float)av.v[7] + hf[a8+7]) * wp[a8+7];
      }
      p += __shfl_xor(p, 1);
      if (half == 0) sexp[l] = __expf(p);
    }
    __syncthreads();
    // ---- softmax normalize (local to WG) ----
    if (t < 64) {
      float z = sexp[t] + sexp[t + 64];
      z += __shfl_xor(z, 32); z += __shfl_xor(z, 16); z += __shfl_xor(z, 8);
      z += __shfl_xor(z, 4);  z += __shfl_xor(z, 2);  z += __shfl_xor(z, 1);
      if (t == 0) zinv_sh = rcp_fast(z);
    }
    __syncthreads();
    if (t < 128) sexp[t] *= zinv_sh;
    __syncthreads();

    // ---- wctx[2t], wctx[2t+1] = sum_l alpha[l] * ctx[b,l,:] ----
    {
      float w0 = 0.f, w1 = 0.f;
      const h16* cb = ctxb + 2 * t;
#pragma unroll 4
      for (int l2 = 0; l2 < 128; l2++) {
        float al = sexp[l2];                    // broadcast
        H2U cu; cu.u = *(const unsigned*)(cb + (size_t)l2 * DD);
        w0 += al * (float)cu.h[0];
        w1 += al * (float)cu.h[1];
      }
      H2U o; o.h = h2{(h16)w0, (h16)w1};
      *(unsigned*)(waux + 2 * t) = o.u;
    }
    __syncthreads();

    // ---- preact[col(t)] = bias + x@W + h@U + wctx@V (one col per thread) ----
    {
      float s = bias_reg;
      for (int kb = 0; kb < 64; kb++) {
        H8 xv; xv.v = *(const h8v*)(xaux + kb * 8);          // broadcast
        H8 hv; hv.v = *(const h8v*)(haux + kb * 8);
        H8 wv; wv.v = *(const h8v*)(waux + kb * 8);
        size_t o = ((size_t)kb * 256 + t) * 8;               // coalesced
        H8 wa; wa.v = *(const h8v*)(myWp + o);
        H8 ua; ua.v = *(const h8v*)(myUp + o);
        H8 va; va.v = *(const h8v*)(myVp + o);
        s = fdot2(xv.p[0], wa.p[0], s); s = fdot2(xv.p[1], wa.p[1], s);
        s = fdot2(xv.p[2], wa.p[2], s); s = fdot2(xv.p[3], wa.p[3], s);
        s = fdot2(hv.p[0], ua.p[0], s); s = fdot2(hv.p[1], ua.p[1], s);
        s = fdot2(hv.p[2], ua.p[2], s); s = fdot2(hv.p[3], ua.p[3], s);
        s = fdot2(wv.p[0], va.p[0], s); s = fdot2(wv.p[1], va.p[1], s);
        s = fdot2(wv.p[2], va.p[2], s); s = fdot2(wv.p[3], va.p[3], s);
      }
      pre[t] = s;
    }
    __syncthreads();

    // ---- gates, c/h update, h store (t<64 own d = 64g+t) ----
    if (t < 64) {
      float pi = pre[t], pf = pre[t + 64], po = pre[t + 128], pg = pre[t + 192];
      float ig = fsig(pi), fg = fsig(pf), og = fsig(po), gg = ftanh(pg);
      float cn = fg * c_reg + ig * gg;
      c_reg = cn;
      float hn = og * ftanh(cn);
      out[((size_t)b * TSTEPS + step) * DD + 64 * g + t] = hn;
      float hn2 = __shfl_xor(hn, 1);
      if ((t & 1) == 0) {
        H2U pu; pu.h = h2{(h16)hn, (h16)hn2};
        cstoreu((unsigned*)(hring + ((size_t)step * 32 + b) * DD + 64 * g + t), pu.u);
      }
    }
    gsync(flags, rel, w, gen);
  }
}

extern "C" void kernel_launch(void* const* d_in, const int* in_sizes, int n_in,
                              void* d_out, int out_size, void* d_ws, size_t ws_size,
                              hipStream_t stream) {
  (void)in_sizes; (void)n_in; (void)out_size; (void)ws_size;
  const float* x    = (const float*)d_in[0];
  const float* ctx  = (const float*)d_in[1];
  const float* W    = (const float*)d_in[2];
  const float* V    = (const float*)d_in[3];
  const float* U    = (const float*)d_in[4];
  const float* b    = (const float*)d_in[5];
  const float* Wh   = (const float*)d_in[6];
  const float* Wc   = (const float*)d_in[7];
  const float* batt = (const float*)d_in[8];
  const float* wprj = (const float*)d_in[9];

  // zero barrier flags + release lines (only state needing init)
  hipMemsetAsync(d_ws, 0, (8192 + 256) * sizeof(int), stream);

  hipLaunchKernelGGL(attn_lstm_persistent, dim3(GD), dim3(BD), 0, stream,
                     x, ctx, W, V, U, b, Wh, Wc, batt, wprj,
                     (float*)d_out, (float*)d_ws);
}

// Round 9
// 6530.256 us; speedup vs baseline: 1.5227x; 1.4935x over previous
//
#include <hip/hip_runtime.h>
#include <hip/hip_fp16.h>

#define GD 256   // grid (workgroups) -- 1 per CU
#define BD 1024  // block: 16 waves/CU for latency hiding (was 256/4 waves)

constexpr int TSTEPS = 256; // sequence length
constexpr int DD = 512;     // d_in = d_out = d_ctx = a_hid
constexpr int KK4 = 2048;   // 4*D_OUT
constexpr int LC = 128;     // context length

// ---- workspace layout ----
constexpr size_t OFF_FLAGS_F = 0;       // 256 flag lines (stride 32 ints)
constexpr size_t OFF_REL_F   = 8192;    // 8 release lines (stride 32 ints)
constexpr size_t OFF_H16_F   = 8448;    // h16 region base (float offset)
// h16-unit offsets inside the h16 region:
constexpr size_t HOFF_ATT   = 0;        // att16 [32][128][512]
constexpr size_t HOFF_CTX   = 2097152;  // ctx16 [32][128][512]
constexpr size_t HOFF_PACK  = 4194304;  // packWUV [8 g][3 mat][64 kb][256 c][8]
constexpr size_t HOFF_WHP   = 7340032;  // Whp [64 kb][512 c][8]
constexpr size_t HOFF_HRING = 7602176;  // hring [256 t][32 b][512]

typedef _Float16 h16;
typedef _Float16 h2  __attribute__((ext_vector_type(2)));
typedef _Float16 h8v __attribute__((ext_vector_type(8)));
union H8  { h8v v; h2 p[4]; };
union H2U { h2 h; unsigned u; };
union HSU { h16 h; unsigned short u; };

__device__ __forceinline__ float rcp_fast(float x) { return __builtin_amdgcn_rcpf(x); }
__device__ __forceinline__ float ftanh(float x) {
  float e = __expf(2.0f * x);
  return 1.0f - 2.0f * rcp_fast(e + 1.0f);
}
__device__ __forceinline__ float fsig(float x) { return rcp_fast(1.0f + __expf(-x)); }
__device__ __forceinline__ float fdot2(h2 a, h2 b, float c) {
  return __builtin_amdgcn_fdot2(a, b, c, false);   // v_dot2_f32_f16
}

// coherent (agent-scope) stores -- reach MALL, visible cross-XCD, no L2 inval
__device__ __forceinline__ void cstoreu(unsigned* p, unsigned v) {
  __hip_atomic_store(p, v, __ATOMIC_RELAXED, __HIP_MEMORY_SCOPE_AGENT);
}
__device__ __forceinline__ void cstores(h16* p, h16 v) {
  HSU s; s.h = v;
  __hip_atomic_store((unsigned short*)p, s.u, __ATOMIC_RELAXED,
                     __HIP_MEMORY_SCOPE_AGENT);
}

// grid barrier, no atomic RMW: per-WG flag lines + WG0 parallel scan + 8 release lines
__device__ __forceinline__ void gsync(int* flags, int* rel, int w, int& gen) {
  __syncthreads();
  gen++;
  const int t = threadIdx.x;
  if (w == 0) {
    if (t < 64) {
      if (t == 0)
        __hip_atomic_store(flags, gen, __ATOMIC_RELAXED, __HIP_MEMORY_SCOPE_AGENT);
      for (;;) {
        int m = gen;
#pragma unroll
        for (int i = 0; i < 4; i++) {
          int v = __hip_atomic_load(flags + (t + i * 64) * 32,
                                    __ATOMIC_RELAXED, __HIP_MEMORY_SCOPE_AGENT);
          m = (v < m) ? v : m;
        }
        if (__all(m >= gen)) break;
      }
      if (t == 0) {
#pragma unroll
        for (int i = 0; i < 8; i++)
          __hip_atomic_store(rel + i * 32, gen, __ATOMIC_RELAXED,
                             __HIP_MEMORY_SCOPE_AGENT);
      }
    }
    asm volatile("" ::: "memory");
  } else {
    if (t == 0) {
      __hip_atomic_store(flags + w * 32, gen, __ATOMIC_RELAXED,
                         __HIP_MEMORY_SCOPE_AGENT);
      const int* r = rel + (w & 7) * 32;
      while (__hip_atomic_load(r, __ATOMIC_RELAXED, __HIP_MEMORY_SCOPE_AGENT) < gen)
        __builtin_amdgcn_s_sleep(1);
    }
    asm volatile("" ::: "memory");
  }
  __syncthreads();
}

__global__ __launch_bounds__(BD, 4) void attn_lstm_persistent(
    const float* __restrict__ x, const float* __restrict__ ctx,
    const float* __restrict__ W, const float* __restrict__ V,
    const float* __restrict__ U, const float* __restrict__ bias,
    const float* __restrict__ Wh, const float* __restrict__ Wc,
    const float* __restrict__ batt, const float* __restrict__ wprj,
    float* __restrict__ out, float* __restrict__ ws) {
  __shared__ float buf[8192];                  // 32 KB, setup staging only
  __shared__ __align__(16) h16 haux[512];      // h_{t-1}[b,:]
  __shared__ __align__(16) h16 xaux[512];      // fp16(x[b,t,:])
  __shared__ __align__(16) h16 waux[512];      // fp16(wctx[b,:])
  __shared__ float hattp[544];                 // h@Wh, padded [8][68] (bank-safe)
  __shared__ float wprjp[544];                 // w_att_prj, padded [8][68]
  __shared__ float hpart[1024];                // hatt partials [2][512]
  __shared__ float sexp[128];                  // exp(prj) -> alpha
  __shared__ float2 wpart[1024];               // wctx partials [4][256]
  __shared__ float pre4[1024];                 // preact partials [4][256]
  __shared__ float pre[256];                   // reduced preact
  __shared__ float zinv_sh;

  const int w = blockIdx.x;
  const int t = threadIdx.x;
  int*  flags = (int*)(ws + OFF_FLAGS_F);
  int*  rel   = (int*)(ws + OFF_REL_F);
  h16*  hb    = (h16*)(ws + OFF_H16_F);
  h16*  att16 = hb + HOFF_ATT;
  h16*  ctx16 = hb + HOFF_CTX;
  h16*  packW = hb + HOFF_PACK;
  h16*  Whp   = hb + HOFF_WHP;
  h16*  hring = hb + HOFF_HRING;
  int gen = 0;

  // XCD-aware (b,g) mapping: per XCD (w%8): 8 distinct b, 4 distinct g
  const int xcd = w & 7, j = w >> 3;
  const int b = (j & 7) | ((xcd >> 1) << 3);   // 0..31
  const int g = (j >> 3) | ((xcd & 1) << 2);   // 0..7

  const int colE = t & 255;                    // preact col for reduce threads
  const int mycol = 64 * g + (colE & 63) + ((colE >> 6) << 9);
  const float bias_reg = bias[mycol];
  float c_reg = 0.f;                           // t<64 own c[b][64g+t]

  // ---- stage wprj into padded LDS ----
  if (t < 512) wprjp[(t >> 6) * 68 + (t & 63)] = wprj[t];

  // ---- setup 1: pack W/U/V cols (WG w packs gg = w>>5, 8 cols jj = w&31) ----
  {
    const int jj = w & 31, gg = w >> 5;
    const int k0 = 2 * (t & 255);
#pragma unroll
    for (int mat = 0; mat < 3; mat++) {
      const float* src = (mat == 0) ? W : ((mat == 1) ? U : V);
      h16* dst = packW + ((size_t)gg * 3 + mat) * 131072;
#pragma unroll
      for (int cc = 0; cc < 2; cc++) {
        int c = 8 * jj + (t >> 8) + 4 * cc;    // col index within [0,256)
        int col = 64 * gg + (c & 63) + ((c >> 6) << 9);
        float v0 = src[(size_t)k0 * KK4 + col];
        float v1 = src[(size_t)(k0 + 1) * KK4 + col];
        H2U pu; pu.h = h2{(h16)v0, (h16)v1};
        cstoreu((unsigned*)(dst + (size_t)(k0 >> 3) * 2048 + c * 8 + (k0 & 7)), pu.u);
      }
    }
    if (w < 64) {                              // pack Wh cols [8w, 8w+8)
#pragma unroll
      for (int cc = 0; cc < 2; cc++) {
        int c = 8 * w + (t >> 8) + 4 * cc;
        float v0 = Wh[(size_t)k0 * DD + c];
        float v1 = Wh[(size_t)(k0 + 1) * DD + c];
        H2U pu; pu.h = h2{(h16)v0, (h16)v1};
        cstoreu((unsigned*)(Whp + (size_t)(k0 >> 3) * 4096 + c * 8 + (k0 & 7)), pu.u);
      }
    }
  }

  // ---- setup 2: ctx16 = fp16(ctx), WG-sliced ----
  {
    const size_t base = (size_t)w * 8192;
#pragma unroll
    for (int i = 0; i < 2; i++) {
      size_t e = base + (size_t)i * 4096 + 4 * t;
      float4 v = *(const float4*)(ctx + e);
      H2U p0; p0.h = h2{(h16)v.x, (h16)v.y};
      H2U p1; p1.h = h2{(h16)v.z, (h16)v.w};
      cstoreu((unsigned*)(ctx16 + e), p0.u);
      cstoreu((unsigned*)(ctx16 + e + 2), p1.u);
    }
  }

  // ---- setup 3: att16 = fp16(ctx @ Wc + b_att), 16 rows per WG ----
  {
    const int r0 = w * 16;
#pragma unroll
    for (int i = 0; i < 2; i++) {
      int idx4 = i * BD + t;
      int row = idx4 >> 7, c4 = idx4 & 127;
      ((float4*)buf)[idx4] = ((const float4*)(ctx + (size_t)(r0 + row) * DD))[c4];
    }
    __syncthreads();
    const int a0 = t & 511, rh = t >> 9;       // col, row-half
    float acc[8];
#pragma unroll
    for (int r = 0; r < 8; r++) acc[r] = 0.f;
    for (int cc = 0; cc < DD; cc++) {
      float wv = Wc[(size_t)cc * DD + a0];
#pragma unroll
      for (int r = 0; r < 8; r++)
        acc[r] += buf[(8 * rh + r) * DD + cc] * wv;   // LDS broadcast per wave
    }
    const float ba = batt[a0];
    for (int r = 0; r < 8; r++)
      cstores(att16 + (size_t)(r0 + 8 * rh + r) * DD + a0, (h16)(acc[r] + ba));
  }
  gsync(flags, rel, w, gen);

  // ---------------- recurrence: ONE grid barrier per step ----------------
  const h16* myWp = packW + (size_t)g * 3 * 131072;
  const h16* myUp = myWp + 131072;
  const h16* myVp = myWp + 262144;
  const h16* attb = att16 + (size_t)b * LC * DD;
  const h16* ctxb = ctx16 + (size_t)b * LC * DD;

  for (int step = 0; step < TSTEPS; step++) {
    // ---- A: load h_{t-1}[b,:] and fp16(x[b,step,:]) into LDS ----
    if (t < 128) {
      if (step > 0) {
        ((uint2*)haux)[t] =
            *(const uint2*)(hring + ((size_t)(step - 1) * 32 + b) * DD + 4 * t);
      } else {
        ((uint2*)haux)[t] = make_uint2(0u, 0u);
      }
      float4 xv = *(const float4*)(x + ((size_t)b * TSTEPS + step) * DD + 4 * t);
      H2U p0; p0.h = h2{(h16)xv.x, (h16)xv.y};
      H2U p1; p1.h = h2{(h16)xv.z, (h16)xv.w};
      ((uint2*)xaux)[t] = make_uint2(p0.u, p1.u);
    }
    __syncthreads();

    // ---- B: hatt = h @ Wh  (512 cols x 2 K-slices) ----
    {
      const int col = t & 511, half = t >> 9;
      const h16* Wp = Whp + (size_t)(32 * half) * 4096 + col * 8;
      float a0 = 0.f;
#pragma unroll 4
      for (int kb = 0; kb < 32; kb++) {
        H8 hv; hv.v = *(const h8v*)(haux + (32 * half + kb) * 8);   // broadcast
        H8 wv; wv.v = *(const h8v*)(Wp + (size_t)kb * 4096);
        a0 = fdot2(hv.p[0], wv.p[0], a0); a0 = fdot2(hv.p[1], wv.p[1], a0);
        a0 = fdot2(hv.p[2], wv.p[2], a0); a0 = fdot2(hv.p[3], wv.p[3], a0);
      }
      hpart[half * 512 + col] = a0;
    }
    __syncthreads();
    if (t < 512) {
      float v = hpart[t] + hpart[512 + t];
      hattp[(t >> 6) * 68 + (t & 63)] = v;     // padded: bank-conflict-free
    }
    __syncthreads();

    // ---- C: scores (128 l x 8 a-slices) ----
    {
      const int l = t >> 3, sl = t & 7;
      const h16* ar = attb + (size_t)l * DD + sl * 64;
      const float* hf = hattp + sl * 68;
      const float* wp = wprjp + sl * 68;
      float p = 0.f;
#pragma unroll
      for (int i = 0; i < 8; i++) {
        H8 av; av.v = *(const h8v*)(ar + i * 8);
        int a8 = i * 8;
        p += ftanh((float)av.v[0] + hf[a8+0]) * wp[a8+0]
           + ftanh((float)av.v[1] + hf[a8+1]) * wp[a8+1]
           + ftanh((float)av.v[2] + hf[a8+2]) * wp[a8+2]
           + ftanh((float)av.v[3] + hf[a8+3]) * wp[a8+3]
           + ftanh((float)av.v[4] + hf[a8+4]) * wp[a8+4]
           + ftanh((float)av.v[5] + hf[a8+5]) * wp[a8+5]
           + ftanh((float)av.v[6] + hf[a8+6]) * wp[a8+6]
           + ftanh((float)av.v[7] + hf[a8+7]) * wp[a8+7];
      }
      p += __shfl_xor(p, 1); p += __shfl_xor(p, 2); p += __shfl_xor(p, 4);
      if (sl == 0) sexp[l] = __expf(p);
    }
    __syncthreads();
    if (t < 64) {
      float z = sexp[t] + sexp[t + 64];
      z += __shfl_xor(z, 32); z += __shfl_xor(z, 16); z += __shfl_xor(z, 8);
      z += __shfl_xor(z, 4);  z += __shfl_xor(z, 2);  z += __shfl_xor(z, 1);
      if (t == 0) zinv_sh = rcp_fast(z);
    }
    __syncthreads();
    if (t < 128) sexp[t] *= zinv_sh;
    __syncthreads();

    // ---- D: wctx (256 col-pairs x 4 l-slices) ----
    {
      const int col2 = t & 255, lq = t >> 8;
      const h16* cb = ctxb + 2 * col2;
      float w0 = 0.f, w1 = 0.f;
#pragma unroll 4
      for (int l2 = 32 * lq; l2 < 32 * lq + 32; l2++) {
        float al = sexp[l2];                   // broadcast (lq uniform per wave)
        H2U cu; cu.u = *(const unsigned*)(cb + (size_t)l2 * DD);
        w0 += al * (float)cu.h[0];
        w1 += al * (float)cu.h[1];
      }
      wpart[lq * 256 + col2] = make_float2(w0, w1);
    }
    __syncthreads();
    if (t < 256) {
      float2 s0 = wpart[t], s1 = wpart[256 + t], s2 = wpart[512 + t], s3 = wpart[768 + t];
      H2U o; o.h = h2{(h16)(s0.x + s1.x + s2.x + s3.x),
                      (h16)(s0.y + s1.y + s2.y + s3.y)};
      *(unsigned*)(waux + 2 * t) = o.u;
    }
    __syncthreads();

    // ---- E: preact (256 cols x 4 K-slices): bias + x@W + h@U + wctx@V ----
    {
      const int col = t & 255, q = t >> 8;
      const size_t kbase = (size_t)(16 * q) * 2048 + col * 8;
      const h16* Wp = myWp + kbase;
      const h16* Up = myUp + kbase;
      const h16* Vp = myVp + kbase;
      float s = 0.f;
#pragma unroll 2
      for (int kb = 0; kb < 16; kb++) {
        int kk = 16 * q + kb;
        H8 xv; xv.v = *(const h8v*)(xaux + kk * 8);          // broadcast
        H8 hv; hv.v = *(const h8v*)(haux + kk * 8);
        H8 wv; wv.v = *(const h8v*)(waux + kk * 8);
        size_t o = (size_t)kb * 2048;
        H8 wa; wa.v = *(const h8v*)(Wp + o);
        H8 ua; ua.v = *(const h8v*)(Up + o);
        H8 va; va.v = *(const h8v*)(Vp + o);
        s = fdot2(xv.p[0], wa.p[0], s); s = fdot2(xv.p[1], wa.p[1], s);
        s = fdot2(xv.p[2], wa.p[2], s); s = fdot2(xv.p[3], wa.p[3], s);
        s = fdot2(hv.p[0], ua.p[0], s); s = fdot2(hv.p[1], ua.p[1], s);
        s = fdot2(hv.p[2], ua.p[2], s); s = fdot2(hv.p[3], ua.p[3], s);
        s = fdot2(wv.p[0], va.p[0], s); s = fdot2(wv.p[1], va.p[1], s);
        s = fdot2(wv.p[2], va.p[2], s); s = fdot2(wv.p[3], va.p[3], s);
      }
      pre4[q * 256 + col] = s;
    }
    __syncthreads();
    if (t < 256)
      pre[t] = pre4[t] + pre4[256 + t] + pre4[512 + t] + pre4[768 + t] + bias_reg;
    __syncthreads();

    // ---- F: gates, c/h update, h store (t<64 own d = 64g+t) ----
    if (t < 64) {
      float pi = pre[t], pf = pre[t + 64], po = pre[t + 128], pg = pre[t + 192];
      float ig = fsig(pi), fg = fsig(pf), og = fsig(po), gg = ftanh(pg);
      float cn = fg * c_reg + ig * gg;
      c_reg = cn;
      float hn = og * ftanh(cn);
      out[((size_t)b * TSTEPS + step) * DD + 64 * g + t] = hn;
      float hn2 = __shfl_xor(hn, 1);
      if ((t & 1) == 0) {
        H2U pu; pu.h = h2{(h16)hn, (h16)hn2};
        cstoreu((unsigned*)(hring + ((size_t)step * 32 + b) * DD + 64 * g + t), pu.u);
      }
    }
    gsync(flags, rel, w, gen);
  }
}

extern "C" void kernel_launch(void* const* d_in, const int* in_sizes, int n_in,
                              void* d_out, int out_size, void* d_ws, size_t ws_size,
                              hipStream_t stream) {
  (void)in_sizes; (void)n_in; (void)out_size; (void)ws_size;
  const float* x    = (const float*)d_in[0];
  const float* ctx  = (const float*)d_in[1];
  const float* W    = (const float*)d_in[2];
  const float* V    = (const float*)d_in[3];
  const float* U    = (const float*)d_in[4];
  const float* b    = (const float*)d_in[5];
  const float* Wh   = (const float*)d_in[6];
  const float* Wc   = (const float*)d_in[7];
  const float* batt = (const float*)d_in[8];
  const float* wprj = (const float*)d_in[9];

  // zero barrier flags + release lines (only state needing init)
  hipMemsetAsync(d_ws, 0, (8192 + 256) * sizeof(int), stream);

  hipLaunchKernelGGL(attn_lstm_persistent, dim3(GD), dim3(BD), 0, stream,
                     x, ctx, W, V, U, b, Wh, Wc, batt, wprj,
                     (float*)d_out, (float*)d_ws);
}

// Round 10
// 6239.393 us; speedup vs baseline: 1.5937x; 1.0466x over previous
//
#include <hip/hip_runtime.h>
#include <hip/hip_fp16.h>

#define GD 256   // grid -- 1 WG per CU
#define BD 1024  // 16 waves/CU

constexpr int TSTEPS = 256;
constexpr int DD = 512;
constexpr int KK4 = 2048;
constexpr int LC = 128;

// ---- ws float offsets ----
constexpr size_t OFF_FLAGS_F = 0;        // 256 flag lines (stride 32 ints)
constexpr size_t OFF_REL_F   = 8192;     // 8 release lines
constexpr size_t OFF_HATTR   = 8448;     // [32][512] f32 hatt exchange (coherent)
constexpr size_t OFF_SEXPR   = 24832;    // [32][128] f32 exp-score exchange
constexpr size_t OFF_H16_F   = 28928;    // h16 region base
// ---- h16-unit offsets ----
constexpr size_t HO_X16   = 0;           // [32][256][512] fp16(x)
constexpr size_t HO_ATT   = 4194304;     // [32*128][512] att_ctx fp16
constexpr size_t HO_HRING = 6291456;     // [256][32][512] h ring fp16
constexpr size_t HO_WCTX  = 10485760;    // [32][512] wctx exchange fp16
constexpr size_t HO_PACK  = 10502144;    // [256][13312] per-WG packed weights
constexpr int PACKSZ = 13312;            // 8W+8U+8V cols (kp-major) + 2 Wh cols

typedef _Float16 h16;
typedef _Float16 h2  __attribute__((ext_vector_type(2)));
typedef _Float16 h4v __attribute__((ext_vector_type(4)));
typedef _Float16 h8v __attribute__((ext_vector_type(8)));
union H8  { h8v v; h2 p[4]; };
union H4  { h4v v; h2 p[2]; };
union H2U { h2 h; unsigned u; };
union HSU { h16 h; unsigned short u; };

__device__ __forceinline__ float rcp_fast(float x) { return __builtin_amdgcn_rcpf(x); }
__device__ __forceinline__ float ftanh(float x) {
  float e = __expf(2.0f * x);
  return 1.0f - 2.0f * rcp_fast(e + 1.0f);
}
__device__ __forceinline__ float fsig(float x) { return rcp_fast(1.0f + __expf(-x)); }
__device__ __forceinline__ float fdot2(h2 a, h2 b, float c) {
  return __builtin_amdgcn_fdot2(a, b, c, false);
}

// agent-scope coherent ops (bypass L1/L2, land at MALL; no cache invalidation)
__device__ __forceinline__ float cloadf(const float* p) {
  return __hip_atomic_load(p, __ATOMIC_RELAXED, __HIP_MEMORY_SCOPE_AGENT);
}
__device__ __forceinline__ void cstoref(float* p, float v) {
  __hip_atomic_store(p, v, __ATOMIC_RELAXED, __HIP_MEMORY_SCOPE_AGENT);
}
__device__ __forceinline__ void cstoreu(unsigned* p, unsigned v) {
  __hip_atomic_store(p, v, __ATOMIC_RELAXED, __HIP_MEMORY_SCOPE_AGENT);
}
__device__ __forceinline__ void cstoreu8(unsigned long long* p, unsigned long long v) {
  __hip_atomic_store(p, v, __ATOMIC_RELAXED, __HIP_MEMORY_SCOPE_AGENT);
}
__device__ __forceinline__ unsigned long long cloadu8(const void* p) {
  return __hip_atomic_load((const unsigned long long*)p, __ATOMIC_RELAXED,
                           __HIP_MEMORY_SCOPE_AGENT);
}
__device__ __forceinline__ void cstores(h16* p, h16 v) {
  HSU s; s.h = v;
  __hip_atomic_store((unsigned short*)p, s.u, __ATOMIC_RELAXED,
                     __HIP_MEMORY_SCOPE_AGENT);
}

// grid barrier, no atomic RMW (R6 design)
__device__ __forceinline__ void gsync(int* flags, int* rel, int w, int& gen) {
  __syncthreads();
  gen++;
  const int t = threadIdx.x;
  if (w == 0) {
    if (t < 64) {
      if (t == 0)
        __hip_atomic_store(flags, gen, __ATOMIC_RELAXED, __HIP_MEMORY_SCOPE_AGENT);
      for (;;) {
        int m = gen;
#pragma unroll
        for (int i = 0; i < 4; i++) {
          int v = __hip_atomic_load(flags + (t + i * 64) * 32,
                                    __ATOMIC_RELAXED, __HIP_MEMORY_SCOPE_AGENT);
          m = (v < m) ? v : m;
        }
        if (__all(m >= gen)) break;
      }
      if (t == 0) {
#pragma unroll
        for (int i = 0; i < 8; i++)
          __hip_atomic_store(rel + i * 32, gen, __ATOMIC_RELAXED,
                             __HIP_MEMORY_SCOPE_AGENT);
      }
    }
    asm volatile("" ::: "memory");
  } else {
    if (t == 0) {
      __hip_atomic_store(flags + w * 32, gen, __ATOMIC_RELAXED,
                         __HIP_MEMORY_SCOPE_AGENT);
      const int* r = rel + (w & 7) * 32;
      while (__hip_atomic_load(r, __ATOMIC_RELAXED, __HIP_MEMORY_SCOPE_AGENT) < gen)
        __builtin_amdgcn_s_sleep(1);
    }
    asm volatile("" ::: "memory");
  }
  __syncthreads();
}

// 8-col GEMV partial over this thread's 8 k-pairs; vec in padded LDS (stride 514)
__device__ __forceinline__ void mac8(const h16* vec, const h16* P, int s, int b,
                                     float* acc) {
  const h16* vrow = vec + b * 514 + 16 * s;
  const h16* Pp = P + (size_t)(8 * s) * 16;
#pragma unroll
  for (int q = 0; q < 8; q++) {
    h2 hv = *(const h2*)(vrow + 2 * q);
    H8 u0; u0.v = *(const h8v*)(Pp + q * 16);
    H8 u1; u1.v = *(const h8v*)(Pp + q * 16 + 8);
#pragma unroll
    for (int j = 0; j < 4; j++) {
      acc[j]     = fdot2(hv, u0.p[j], acc[j]);
      acc[4 + j] = fdot2(hv, u1.p[j], acc[4 + j]);
    }
  }
}

__global__ __launch_bounds__(BD, 4) void attn_lstm_persistent(
    const float* __restrict__ x, const float* __restrict__ ctx,
    const float* __restrict__ W, const float* __restrict__ V,
    const float* __restrict__ U, const float* __restrict__ bias,
    const float* __restrict__ Wh, const float* __restrict__ Wc,
    const float* __restrict__ batt, const float* __restrict__ wprj,
    float* __restrict__ out, float* __restrict__ ws) {
  __shared__ __align__(16) unsigned char smem[62144];
  h16*   haux  = (h16*)smem;                    // 32 x 514 h16 (padded) = 32896 B
  float* red   = (float*)(smem + 32896);        // 16 x 320 f32 = 20480 B
  float* hUk   = (float*)(smem + 53376);        // [8 c][32 b]
  float* xwk   = (float*)(smem + 54400);        // [2][8 c][32 b]
  float* hattp = (float*)(smem + 56448);        // 512
  float* sexps = (float*)(smem + 58496);        // 128
  float* wprjs = (float*)(smem + 59008);        // 512
  float* pre   = (float*)(smem + 61056);        // [8 c][32 b]
  float* bias8 = (float*)(smem + 62080);        // 8
  float* zinv  = (float*)(smem + 62112);

  const int w = blockIdx.x;
  const int t = threadIdx.x;
  int*   flags = (int*)(ws + OFF_FLAGS_F);
  int*   rel   = (int*)(ws + OFF_REL_F);
  float* hattr = ws + OFF_HATTR;
  float* sexpr = ws + OFF_SEXPR;
  h16*   hb    = (h16*)(ws + OFF_H16_F);
  h16*   x16   = hb + HO_X16;
  h16*   att16 = hb + HO_ATT;
  h16*   hring = hb + HO_HRING;
  h16*   wctxr = hb + HO_WCTX;
  h16*   packA = hb + HO_PACK;
  const h16* mypack = packA + (size_t)w * PACKSZ;
  const h16* PW  = mypack;            // x@W cols
  const h16* PU  = mypack + 4096;     // h@U cols
  const h16* PV  = mypack + 8192;     // wctx@V cols
  const h16* PWh = mypack + 12288;    // h@Wh cols (2)
  int gen = 0;

  float c_reg = 0.f;                  // t<64 own c[b = t&31][2w + (t>>5)]

  // ================= setup =================
  // pack W/U/V/Wh transposed-cooperatively: WG w owns k-pair kp=w (rows 2w,2w+1)
  {
    const int kp = w;
    const float* srcs[3] = {W, U, V};
#pragma unroll
    for (int mat = 0; mat < 3; mat++) {
      const float* s0 = srcs[mat] + (size_t)(2 * kp) * KK4;
      const float* s1 = s0 + KK4;
#pragma unroll
      for (int rep = 0; rep < 2; rep++) {
        int col = t + rep * 1024;
        float v0 = s0[col], v1 = s1[col];
        int wo = (col & 511) >> 1;
        int cc = (col & 1) + ((col >> 9) << 1);
        H2U pu; pu.h = h2{(h16)v0, (h16)v1};
        cstoreu((unsigned*)(packA + (size_t)wo * PACKSZ + mat * 4096 + kp * 16 + cc * 2),
                pu.u);
      }
    }
    if (t < 512) {
      int col = t;
      float v0 = Wh[(size_t)(2 * kp) * DD + col];
      float v1 = Wh[(size_t)(2 * kp + 1) * DD + col];
      int wo = col >> 1, cc = col & 1;
      H2U pu; pu.h = h2{(h16)v0, (h16)v1};
      cstoreu((unsigned*)(packA + (size_t)wo * PACKSZ + 12288 + kp * 4 + cc * 2), pu.u);
    }
  }
  // x16 = fp16(x), WG-sliced linear
  {
    size_t i0 = (size_t)w * 16384 + (size_t)t * 16;
#pragma unroll
    for (int q = 0; q < 4; q++) {
      float4 v = *(const float4*)(x + i0 + q * 4);
      H2U lo; lo.h = h2{(h16)v.x, (h16)v.y};
      H2U hi; hi.h = h2{(h16)v.z, (h16)v.w};
      unsigned long long pk = (unsigned long long)lo.u | ((unsigned long long)hi.u << 32);
      cstoreu8((unsigned long long*)(x16 + i0 + q * 4), pk);
    }
  }
  // att16 = fp16(ctx @ Wc + b_att), 16 rows per WG (rows = b*128+l)
  {
    float* fbuf = (float*)smem;                   // 32 KB staging
    const int r0 = w * 16;
#pragma unroll
    for (int i = 0; i < 2; i++) {
      int idx4 = i * BD + t;
      int row = idx4 >> 7, c4 = idx4 & 127;
      ((float4*)fbuf)[idx4] = ((const float4*)(ctx + (size_t)(r0 + row) * DD))[c4];
    }
    __syncthreads();
    const int a0 = t & 511, rh = t >> 9;
    float acc[8];
#pragma unroll
    for (int r = 0; r < 8; r++) acc[r] = 0.f;
    for (int cc = 0; cc < DD; cc++) {
      float wv = Wc[(size_t)cc * DD + a0];
#pragma unroll
      for (int r = 0; r < 8; r++)
        acc[r] += fbuf[(8 * rh + r) * DD + cc] * wv;
    }
    const float ba = batt[a0];
    for (int r = 0; r < 8; r++)
      cstores(att16 + (size_t)(r0 + 8 * rh + r) * DD + a0, (h16)(acc[r] + ba));
    __syncthreads();
  }
  // stage wprj + bias8
  if (t < 512) wprjs[t] = wprj[t];
  if (t < 8) bias8[t] = bias[2 * w + (t & 1) + (t >> 1) * 512];
  gsync(flags, rel, w, gen);

  // xw for step 0: stage x16[:,0,:] into haux, compute 8-col partials -> xwk[0]
  {
    const int bb = t >> 5, ch = t & 31;
    const uint4* sp = (const uint4*)(x16 + ((size_t)bb * TSTEPS + 0) * DD + ch * 16);
    uint4 v0 = sp[0], v1 = sp[1];
    unsigned* dp = (unsigned*)(haux + bb * 514 + ch * 16);
    dp[0] = v0.x; dp[1] = v0.y; dp[2] = v0.z; dp[3] = v0.w;
    dp[4] = v1.x; dp[5] = v1.y; dp[6] = v1.z; dp[7] = v1.w;
    __syncthreads();
    const int b = t & 31, s = t >> 5;
    float acc[8] = {0.f,0.f,0.f,0.f,0.f,0.f,0.f,0.f};
    mac8(haux, PW, s, b, acc);
#pragma unroll
    for (int c = 0; c < 8; c++) acc[c] += __shfl_xor(acc[c], 32);
    if ((t & 32) == 0) {
      int s2 = t >> 6;
#pragma unroll
      for (int c = 0; c < 8; c++) red[s2 * 256 + c * 32 + b] = acc[c];
    }
    __syncthreads();
    if (t < 256) {
      float sm = 0.f;
#pragma unroll
      for (int j2 = 0; j2 < 16; j2++) sm += red[j2 * 256 + t];
      xwk[t] = sm;
    }
    __syncthreads();
  }

  // ================= recurrence: 4 grid barriers/step =================
  for (int step = 0; step < TSTEPS; step++) {
    // ---- S1: load h_{t-1}; hU (8 cols -> hUk) + hatt (2 cols -> MALL) ----
    {
      const int bb = t >> 5, ch = t & 31;
      uint4 v0 = make_uint4(0,0,0,0), v1 = make_uint4(0,0,0,0);
      if (step > 0) {
        const uint4* sp =
            (const uint4*)(hring + ((size_t)(step - 1) * 32 + bb) * DD + ch * 16);
        v0 = sp[0]; v1 = sp[1];
      }
      unsigned* dp = (unsigned*)(haux + bb * 514 + ch * 16);
      dp[0] = v0.x; dp[1] = v0.y; dp[2] = v0.z; dp[3] = v0.w;
      dp[4] = v1.x; dp[5] = v1.y; dp[6] = v1.z; dp[7] = v1.w;
      __syncthreads();
      const int b = t & 31, s = t >> 5;
      float acc[10];
#pragma unroll
      for (int i = 0; i < 10; i++) acc[i] = 0.f;
      mac8(haux, PU, s, b, acc);
      {
        const h16* vrow = haux + b * 514 + 16 * s;
        const h16* Pp = PWh + (size_t)(8 * s) * 4;
#pragma unroll
        for (int q = 0; q < 8; q++) {
          h2 hv = *(const h2*)(vrow + 2 * q);
          H4 whv; whv.v = *(const h4v*)(Pp + q * 4);
          acc[8] = fdot2(hv, whv.p[0], acc[8]);
          acc[9] = fdot2(hv, whv.p[1], acc[9]);
        }
      }
#pragma unroll
      for (int c = 0; c < 10; c++) acc[c] += __shfl_xor(acc[c], 32);
      if ((t & 32) == 0) {
        int s2 = t >> 6;
#pragma unroll
        for (int c = 0; c < 10; c++) red[s2 * 320 + c * 32 + b] = acc[c];
      }
      __syncthreads();
      if (t < 320) {
        float sm = 0.f;
#pragma unroll
        for (int j2 = 0; j2 < 16; j2++) sm += red[j2 * 320 + t];
        int c = t >> 5, b2 = t & 31;
        if (c < 8) hUk[c * 32 + b2] = sm;
        else cstoref(hattr + (size_t)b2 * DD + 2 * w + (c - 8), sm);
      }
    }
    gsync(flags, rel, w, gen);

    // ---- S2: scores for (b = w>>3, 16 l's) -> sexpr; prefetch xw[step+1] ----
    {
      const int b2 = w >> 3, l0 = (w & 7) * 16;
      if (t < 512) hattp[t] = cloadf(hattr + (size_t)b2 * DD + t);
      __syncthreads();
      {
        const int l = t >> 6, as = t & 63;
        const h16* arow = att16 + (size_t)(b2 * LC + l0 + l) * DD;
        float p = 0.f;
#pragma unroll
        for (int j2 = 0; j2 < 8; j2++) {
          int a = as + 64 * j2;
          float av = (float)arow[a];
          p += ftanh(av + hattp[a]) * wprjs[a];
        }
        p += __shfl_xor(p, 1);  p += __shfl_xor(p, 2);  p += __shfl_xor(p, 4);
        p += __shfl_xor(p, 8);  p += __shfl_xor(p, 16); p += __shfl_xor(p, 32);
        if (as == 0) cstoref(sexpr + (size_t)b2 * LC + l0 + l, __expf(p));
      }
      if (step + 1 < TSTEPS) {
        const int bb = t >> 5, ch = t & 31;
        const uint4* sp =
            (const uint4*)(x16 + ((size_t)bb * TSTEPS + step + 1) * DD + ch * 16);
        uint4 v0 = sp[0], v1 = sp[1];
        __syncthreads();                      // scores done reading haux? (haux unused) -- protects red
        unsigned* dp = (unsigned*)(haux + bb * 514 + ch * 16);
        dp[0] = v0.x; dp[1] = v0.y; dp[2] = v0.z; dp[3] = v0.w;
        dp[4] = v1.x; dp[5] = v1.y; dp[6] = v1.z; dp[7] = v1.w;
        __syncthreads();
        const int b = t & 31, s = t >> 5;
        float acc[8] = {0.f,0.f,0.f,0.f,0.f,0.f,0.f,0.f};
        mac8(haux, PW, s, b, acc);
#pragma unroll
        for (int c = 0; c < 8; c++) acc[c] += __shfl_xor(acc[c], 32);
        if ((t & 32) == 0) {
          int s2 = t >> 6;
#pragma unroll
          for (int c = 0; c < 8; c++) red[s2 * 256 + c * 32 + b] = acc[c];
        }
        __syncthreads();
        if (t < 256) {
          float sm = 0.f;
#pragma unroll
          for (int j2 = 0; j2 < 16; j2++) sm += red[j2 * 256 + t];
          xwk[((step + 1) & 1) * 256 + t] = sm;
        }
      }
    }
    gsync(flags, rel, w, gen);

    // ---- S3: wctx for (b = w>>3, 64 cols cs = w&7) -> wctxr (fp16, MALL) ----
    {
      const int b3 = w >> 3, cs = w & 7;
      if (t < 128) sexps[t] = cloadf(sexpr + (size_t)b3 * LC + t);
      __syncthreads();
      if (t < 64) {
        float z = sexps[t] + sexps[t + 64];
        z += __shfl_xor(z, 32); z += __shfl_xor(z, 16); z += __shfl_xor(z, 8);
        z += __shfl_xor(z, 4);  z += __shfl_xor(z, 2);  z += __shfl_xor(z, 1);
        if (t == 0) *zinv = rcp_fast(z);
      }
      __syncthreads();
      const float zi = *zinv;
      const int lsl = t & 15, c = t >> 4;
      float acc = 0.f;
#pragma unroll
      for (int j2 = 0; j2 < 8; j2++) {
        int l = lsl + 16 * j2;
        float al = sexps[l];
        float cv = ctx[(size_t)(b3 * LC + l) * DD + cs * 64 + c];
        acc += al * cv;
      }
      acc += __shfl_xor(acc, 1); acc += __shfl_xor(acc, 2);
      acc += __shfl_xor(acc, 4); acc += __shfl_xor(acc, 8);
      if (lsl == 0)
        cstores(wctxr + (size_t)b3 * DD + cs * 64 + c, (h16)(acc * zi));
    }
    gsync(flags, rel, w, gen);

    // ---- S4: preact = xw + hU + wctx@V + bias; gates; h out ----
    {
      const int bb = t >> 5, ch = t & 31;
      const h16* src = wctxr + (size_t)bb * DD + ch * 16;
      unsigned long long q0 = cloadu8(src),     q1 = cloadu8(src + 4);
      unsigned long long q2 = cloadu8(src + 8), q3 = cloadu8(src + 12);
      unsigned* dp = (unsigned*)(haux + bb * 514 + ch * 16);
      dp[0] = (unsigned)q0; dp[1] = (unsigned)(q0 >> 32);
      dp[2] = (unsigned)q1; dp[3] = (unsigned)(q1 >> 32);
      dp[4] = (unsigned)q2; dp[5] = (unsigned)(q2 >> 32);
      dp[6] = (unsigned)q3; dp[7] = (unsigned)(q3 >> 32);
      __syncthreads();
      const int b = t & 31, s = t >> 5;
      float acc[8] = {0.f,0.f,0.f,0.f,0.f,0.f,0.f,0.f};
      mac8(haux, PV, s, b, acc);
#pragma unroll
      for (int c = 0; c < 8; c++) acc[c] += __shfl_xor(acc[c], 32);
      if ((t & 32) == 0) {
        int s2 = t >> 6;
#pragma unroll
        for (int c = 0; c < 8; c++) red[s2 * 256 + c * 32 + b] = acc[c];
      }
      __syncthreads();
      if (t < 256) {
        float sm = 0.f;
#pragma unroll
        for (int j2 = 0; j2 < 16; j2++) sm += red[j2 * 256 + t];
        int c = t >> 5;
        pre[t] = sm + hUk[t] + xwk[(step & 1) * 256 + t] + bias8[c];
      }
      __syncthreads();
      if (t < 64) {
        const int b3 = t & 31, dd = t >> 5;
        float pi = pre[(0 + dd) * 32 + b3];
        float pf = pre[(2 + dd) * 32 + b3];
        float po = pre[(4 + dd) * 32 + b3];
        float pg = pre[(6 + dd) * 32 + b3];
        float ig = fsig(pi), fg = fsig(pf), og = fsig(po), gg = ftanh(pg);
        float cn = fg * c_reg + ig * gg;
        c_reg = cn;
        float hn = og * ftanh(cn);
        out[((size_t)b3 * TSTEPS + step) * DD + 2 * w + dd] = hn;
        float hn2 = __shfl_xor(hn, 32);
        if (t < 32) {
          H2U pu; pu.h = h2{(h16)hn, (h16)hn2};
          cstoreu((unsigned*)(hring + ((size_t)step * 32 + b3) * DD + 2 * w), pu.u);
        }
      }
    }
    gsync(flags, rel, w, gen);
  }
}

extern "C" void kernel_launch(void* const* d_in, const int* in_sizes, int n_in,
                              void* d_out, int out_size, void* d_ws, size_t ws_size,
                              hipStream_t stream) {
  (void)in_sizes; (void)n_in; (void)out_size; (void)ws_size;
  const float* x    = (const float*)d_in[0];
  const float* ctx  = (const float*)d_in[1];
  const float* W    = (const float*)d_in[2];
  const float* V    = (const float*)d_in[3];
  const float* U    = (const float*)d_in[4];
  const float* b    = (const float*)d_in[5];
  const float* Wh   = (const float*)d_in[6];
  const float* Wc   = (const float*)d_in[7];
  const float* batt = (const float*)d_in[8];
  const float* wprj = (const float*)d_in[9];

  hipMemsetAsync(d_ws, 0, (8192 + 256) * sizeof(int), stream);

  hipLaunchKernelGGL(attn_lstm_persistent, dim3(GD), dim3(BD), 0, stream,
                     x, ctx, W, V, U, b, Wh, Wc, batt, wprj,
                     (float*)d_out, (float*)d_ws);
}